// Round 1
// baseline (548.151 us; speedup 1.0000x reference)
//
#include <hip/hip_runtime.h>
#include <math.h>

// Shapes (fixed by the reference)
#define NN 512
#define MM 512
#define QQ 128
#define HH 8
#define DD 16
#define HD 128   // H*D

// ---------------------------------------------------------------------------
// pack: Wc[q][o] (o<128 -> lambda_z1[h][q][d], o>=128 -> lambda_z2), o=h*16+d
//       T2[o][q] = theta2[h][q][d]
//       ob[q]    = sum_{h,d} bias_theta[h][d] * theta2[h][q][d]
// ---------------------------------------------------------------------------
__global__ void pack_kernel(const float* __restrict__ lz1,
                            const float* __restrict__ lz2,
                            const float* __restrict__ th2,
                            const float* __restrict__ bth,
                            float* __restrict__ Wc,
                            float* __restrict__ T2,
                            float* __restrict__ ob) {
    int tid = blockIdx.x * blockDim.x + threadIdx.x;
    int stride = gridDim.x * blockDim.x;
    for (int i = tid; i < 128 * 256; i += stride) {
        int q = i >> 8, o = i & 255;
        int oo = o & 127;
        int h = oo >> 4, d = oo & 15;
        float v = (o < 128) ? lz1[(h * 128 + q) * 16 + d]
                            : lz2[(h * 128 + q) * 16 + d];
        Wc[i] = v;
    }
    for (int i = tid; i < 128 * 128; i += stride) {
        int o = i >> 7, q = i & 127;
        int h = o >> 4, d = o & 15;
        T2[i] = th2[(h * 128 + q) * 16 + d];
    }
    for (int q = tid; q < 128; q += stride) {
        float s = 0.f;
        for (int h = 0; h < 8; ++h)
            for (int d = 0; d < 16; ++d)
                s += bth[h * 16 + d] * th2[(h * 128 + q) * 16 + d];
        ob[q] = s;
    }
}

// ---------------------------------------------------------------------------
// proj: which=0: rx = x @ lambda_x + bias   (out layout [n][h*16+d])
//       which=1: ry = y @ lambda_y + bias
//       which=2: xp = x @ theta1
// ---------------------------------------------------------------------------
__global__ void proj_kernel(const float* __restrict__ x,
                            const float* __restrict__ y,
                            const float* __restrict__ lx,
                            const float* __restrict__ ly,
                            const float* __restrict__ t1,
                            const float* __restrict__ blx,
                            const float* __restrict__ bly,
                            float* __restrict__ rx,
                            float* __restrict__ ry,
                            float* __restrict__ xp) {
    __shared__ float row[128];
    int n = blockIdx.x;
    int which = blockIdx.y;
    const float* in = (which == 1) ? y : x;
    const float* L  = (which == 0) ? lx : (which == 1) ? ly : t1;
    int o = threadIdx.x;               // 0..127  (h*16+d)
    row[o] = in[n * 128 + o];
    __syncthreads();
    int h = o >> 4, d = o & 15;
    float acc = 0.f;
    for (int q = 0; q < 128; ++q)
        acc = fmaf(row[q], L[(h * 128 + q) * 16 + d], acc);
    if (which == 0) acc += blx[o];
    if (which == 1) acc += bly[o];
    float* dst = (which == 0) ? rx : (which == 1) ? ry : xp;
    dst[n * 128 + o] = acc;
}

// ---------------------------------------------------------------------------
// big: per block (n fixed, 128-m tile): for each edge compute
//      r_z1, r_z2 = z[n,m,:] @ Wc, then att[h][n][m] after tanh/clip/mask.
// Thread layout: tid = te*16 + tO. te(0..15) owns 8 edges, tO(0..15) owns
// (head-quad, d-group): pass p covers heads p*4..p*4+3.
// ---------------------------------------------------------------------------
__global__ __launch_bounds__(256) void big_kernel(
        const float* __restrict__ z,
        const int* __restrict__ mask,
        const float* __restrict__ Wc,
        const float* __restrict__ rx,
        const float* __restrict__ ry,
        float* __restrict__ att) {
    __shared__ float zs[128][128];          // 64 KB: z[m0+e][q]
    const int m0 = blockIdx.x * 128;
    const int n  = blockIdx.y;
    const int tid = threadIdx.x;
    const int tO = tid & 15;
    const int te = tid >> 4;

    // stage z tile (coalesced float4)
    for (int idx = tid; idx < 128 * 32; idx += 256) {
        int r = idx >> 5, c4 = idx & 31;
        float4 v = *(const float4*)&z[((size_t)(n * 512 + m0 + r)) * 128 + c4 * 4];
        *(float4*)&zs[r][c4 * 4] = v;
    }
    __syncthreads();

    for (int p = 0; p < 2; ++p) {
        const int h  = p * 4 + (tO >> 2);
        const int dg = tO & 3;
        const int o1 = p * 64 + tO * 4;     // == h*16 + dg*4
        const int o2 = 128 + o1;

        float acc1[8][4], acc2[8][4];
#pragma unroll
        for (int i = 0; i < 8; ++i)
#pragma unroll
            for (int j = 0; j < 4; ++j) { acc1[i][j] = 0.f; acc2[i][j] = 0.f; }

        for (int k = 0; k < 128; k += 4) {
            float wa[4][4], wb[4][4];
#pragma unroll
            for (int kk = 0; kk < 4; ++kk) {
                float4 t = *(const float4*)&Wc[(k + kk) * 256 + o1];
                wa[kk][0] = t.x; wa[kk][1] = t.y; wa[kk][2] = t.z; wa[kk][3] = t.w;
                float4 u = *(const float4*)&Wc[(k + kk) * 256 + o2];
                wb[kk][0] = u.x; wb[kk][1] = u.y; wb[kk][2] = u.z; wb[kk][3] = u.w;
            }
#pragma unroll
            for (int i = 0; i < 8; ++i) {
                float4 zt = *(const float4*)&zs[te * 8 + i][k];
                float zv[4] = {zt.x, zt.y, zt.z, zt.w};
#pragma unroll
                for (int kk = 0; kk < 4; ++kk)
#pragma unroll
                    for (int j = 0; j < 4; ++j) {
                        acc1[i][j] = fmaf(zv[kk], wa[kk][j], acc1[i][j]);
                        acc2[i][j] = fmaf(zv[kk], wb[kk][j], acc2[i][j]);
                    }
            }
        }

        // att assembly: att = sum_d (rx+rz1)*(ry+rz2), quad-reduce over d-groups
        float4 rxt = *(const float4*)&rx[n * 128 + h * 16 + dg * 4];
        float rxv[4] = {rxt.x, rxt.y, rxt.z, rxt.w};
#pragma unroll
        for (int i = 0; i < 8; ++i) {
            int m = m0 + te * 8 + i;
            float4 ryt = *(const float4*)&ry[m * 128 + h * 16 + dg * 4];
            float ryv[4] = {ryt.x, ryt.y, ryt.z, ryt.w};
            float pa = 0.f;
#pragma unroll
            for (int j = 0; j < 4; ++j)
                pa = fmaf(rxv[j] + acc1[i][j], ryv[j] + acc2[i][j], pa);
            pa += __shfl_xor(pa, 1);
            pa += __shfl_xor(pa, 2);
            if (dg == 0) {
                float a = 10.f * tanhf(0.25f * pa);
                if (mask[n * 512 + m] == 1) a = -INFINITY;
                att[((size_t)(h * 512 + n)) * 512 + m] = a;
            }
        }
    }
}

// ---------------------------------------------------------------------------
// softpv: softmax over n for each (h,m), then r[m][h*16+d] = sum_n w * xp
// block: (mb, h), 128 threads = 32 m * 4 d-subgroups (each redundantly scans n)
// ---------------------------------------------------------------------------
__global__ void softpv_kernel(const float* __restrict__ att,
                              const float* __restrict__ xp,
                              float* __restrict__ rr) {
    __shared__ float xps[512][16];          // 32 KB: xp[n][h*16 + 0..15]
    const int mb = blockIdx.x;
    const int h  = blockIdx.y;
    const int tid = threadIdx.x;
    for (int idx = tid; idx < 512 * 4; idx += 128) {
        int r = idx >> 2, c = idx & 3;
        float4 v = *(const float4*)&xp[r * 128 + h * 16 + c * 4];
        *(float4*)&xps[r][c * 4] = v;
    }
    __syncthreads();

    const int m   = mb * 32 + (tid >> 2);
    const int sub = tid & 3;

    const float* col = &att[((size_t)h * 512) * 512 + m];
    float mx = -INFINITY;
    for (int nn = 0; nn < 512; ++nn)
        mx = fmaxf(mx, col[nn * 512]);

    float s = 0.f;
    float racc[4] = {0.f, 0.f, 0.f, 0.f};
    for (int nn = 0; nn < 512; ++nn) {
        float e = __expf(col[nn * 512] - mx);
        s += e;
#pragma unroll
        for (int dd = 0; dd < 4; ++dd)
            racc[dd] = fmaf(e, xps[nn][sub * 4 + dd], racc[dd]);
    }
    float inv = 1.f / s;
#pragma unroll
    for (int dd = 0; dd < 4; ++dd)
        rr[m * 128 + h * 16 + sub * 4 + dd] = racc[dd] * inv;
}

// ---------------------------------------------------------------------------
// outg: out[m][q] = ob[q] + sum_o rr[m][o] * T2[o][q]
// ---------------------------------------------------------------------------
__global__ void outg_kernel(const float* __restrict__ rr,
                            const float* __restrict__ T2,
                            const float* __restrict__ ob,
                            float* __restrict__ out) {
    int m = blockIdx.x;
    int q = threadIdx.x;
    float s = ob[q];
    for (int o = 0; o < 128; ++o)
        s = fmaf(rr[m * 128 + o], T2[o * 128 + q], s);
    out[m * 128 + q] = s;
}

extern "C" void kernel_launch(void* const* d_in, const int* in_sizes, int n_in,
                              void* d_out, int out_size, void* d_ws, size_t ws_size,
                              hipStream_t stream) {
    (void)in_sizes; (void)n_in; (void)out_size; (void)ws_size;
    const float* x   = (const float*)d_in[0];
    const float* y   = (const float*)d_in[1];
    const float* z   = (const float*)d_in[2];
    const int*  mask = (const int*)d_in[3];
    const float* lx  = (const float*)d_in[4];
    const float* ly  = (const float*)d_in[5];
    const float* lz1 = (const float*)d_in[6];
    const float* lz2 = (const float*)d_in[7];
    const float* blx = (const float*)d_in[8];
    const float* bly = (const float*)d_in[9];
    const float* t1  = (const float*)d_in[10];
    const float* t2  = (const float*)d_in[11];
    const float* bth = (const float*)d_in[12];
    float* out = (float*)d_out;

    float* ws  = (float*)d_ws;
    float* rx  = ws;                 // 65536
    float* ry  = rx + 65536;         // 65536
    float* xp  = ry + 65536;         // 65536
    float* Wc  = xp + 65536;         // 32768
    float* T2  = Wc + 32768;         // 16384
    float* ob  = T2 + 16384;         // 128
    float* att = ob + 128;           // 8*512*512 = 2097152
    float* rr  = att + 2097152;      // 65536

    pack_kernel<<<dim3(32), dim3(256), 0, stream>>>(lz1, lz2, t2, bth, Wc, T2, ob);
    proj_kernel<<<dim3(512, 3), dim3(128), 0, stream>>>(x, y, lx, ly, t1, blx, bly, rx, ry, xp);
    big_kernel<<<dim3(4, 512), dim3(256), 0, stream>>>(z, mask, Wc, rx, ry, att);
    softpv_kernel<<<dim3(16, 8), dim3(128), 0, stream>>>(att, xp, rr);
    outg_kernel<<<dim3(512), dim3(128), 0, stream>>>(rr, T2, ob, out);
}

// Round 3
// 372.690 us; speedup vs baseline: 1.4708x; 1.4708x over previous
//
#include <hip/hip_runtime.h>
#include <hip/hip_bf16.h>
#include <math.h>

typedef __attribute__((ext_vector_type(8))) short short8;
typedef __attribute__((ext_vector_type(4))) float f32x4;

// ---------------------------------------------------------------------------
// pack: Wh/Wl[o'][q] bf16 hi/lo, o' = h*32 + which*16 + d  (which0=lambda_z1)
//       T2[o][q] = theta2[h][q][d] (o=h*16+d);  ob[q] = sum bias_theta*theta2
// ---------------------------------------------------------------------------
__global__ void pack_kernel(const float* __restrict__ lz1,
                            const float* __restrict__ lz2,
                            const float* __restrict__ th2,
                            const float* __restrict__ bth,
                            __hip_bfloat16* __restrict__ Wh,
                            __hip_bfloat16* __restrict__ Wl,
                            float* __restrict__ T2,
                            float* __restrict__ ob) {
    int tid = blockIdx.x * blockDim.x + threadIdx.x;
    int stride = gridDim.x * blockDim.x;
    for (int i = tid; i < 256 * 128; i += stride) {
        int op = i >> 7, q = i & 127;
        int h = op >> 5, wh = (op >> 4) & 1, d = op & 15;
        float v = (wh ? lz2 : lz1)[(h * 128 + q) * 16 + d];
        __hip_bfloat16 hb = __float2bfloat16(v);
        Wh[i] = hb;
        Wl[i] = __float2bfloat16(v - __bfloat162float(hb));
    }
    for (int i = tid; i < 128 * 128; i += stride) {
        int o = i >> 7, q = i & 127;
        int h = o >> 4, d = o & 15;
        T2[i] = th2[(h * 128 + q) * 16 + d];
    }
    for (int q = tid; q < 128; q += stride) {
        float s = 0.f;
        for (int h = 0; h < 8; ++h)
            for (int d = 0; d < 16; ++d)
                s += bth[h * 16 + d] * th2[(h * 128 + q) * 16 + d];
        ob[q] = s;
    }
}

// ---------------------------------------------------------------------------
// proj: which=0: rx = x@lambda_x + b; 1: ry = y@lambda_y + b; 2: xp = x@theta1
// out layout [n][h*16+d]
// ---------------------------------------------------------------------------
__global__ void proj_kernel(const float* __restrict__ x,
                            const float* __restrict__ y,
                            const float* __restrict__ lx,
                            const float* __restrict__ ly,
                            const float* __restrict__ t1,
                            const float* __restrict__ blx,
                            const float* __restrict__ bly,
                            float* __restrict__ rx,
                            float* __restrict__ ry,
                            float* __restrict__ xp) {
    __shared__ float row[128];
    int n = blockIdx.x;
    int which = blockIdx.y;
    const float* in = (which == 1) ? y : x;
    const float* L  = (which == 0) ? lx : (which == 1) ? ly : t1;
    int o = threadIdx.x;
    row[o] = in[n * 128 + o];
    __syncthreads();
    int h = o >> 4, d = o & 15;
    float acc = 0.f;
    for (int q = 0; q < 128; ++q)
        acc = fmaf(row[q], L[(h * 128 + q) * 16 + d], acc);
    if (which == 0) acc += blx[o];
    if (which == 1) acc += bly[o];
    float* dst = (which == 0) ? rx : (which == 1) ? ry : xp;
    dst[n * 128 + o] = acc;
}

// ---------------------------------------------------------------------------
// big: per block (n, 128-m tile): bf16x3 MFMA z-projection (K=128, O=256),
// then att = sum_d (rx+rz1)(ry+rz2) via 16-lane shfl reduce, tanh/clip/mask.
// 8 waves = 2 edge-groups(64) x 4 o-groups(64 = heads 2og,2og+1 interleaved).
// ---------------------------------------------------------------------------
__global__ __launch_bounds__(512) void big_kernel(
        const float* __restrict__ z,
        const int* __restrict__ mask,
        const __hip_bfloat16* __restrict__ Wh,
        const __hip_bfloat16* __restrict__ Wl,
        const float* __restrict__ rx,
        const float* __restrict__ ry,
        float* __restrict__ att) {
    __shared__ short zsh[128 * 128];   // 32 KB bf16-hi, XOR-swizzled 16B chunks
    __shared__ short zsl[128 * 128];   // 32 KB bf16-lo
    const int m0 = blockIdx.x * 128;
    const int n  = blockIdx.y;
    const int tid = threadIdx.x;

    // ---- stage z tile: fp32 -> bf16 hi/lo, swizzle chunk ^= (row&7) ----
    {
        const int row = tid >> 2, kseg = tid & 3;
        const float* src = &z[((size_t)(n * 512 + m0 + row)) * 128 + kseg * 32];
#pragma unroll
        for (int c8 = 0; c8 < 4; ++c8) {
            float4 v0 = *(const float4*)&src[c8 * 8 + 0];
            float4 v1 = *(const float4*)&src[c8 * 8 + 4];
            float vv[8] = {v0.x, v0.y, v0.z, v0.w, v1.x, v1.y, v1.z, v1.w};
            union { short8 s; __hip_bfloat16 h[8]; } uh, ul;
#pragma unroll
            for (int j = 0; j < 8; ++j) {
                float f = vv[j];
                __hip_bfloat16 hb = __float2bfloat16(f);
                uh.h[j] = hb;
                ul.h[j] = __float2bfloat16(f - __bfloat162float(hb));
            }
            int cw = (kseg * 4 + c8) ^ (row & 7);
            *(short8*)&zsh[row * 128 + cw * 8] = uh.s;
            *(short8*)&zsl[row * 128 + cw * 8] = ul.s;
        }
    }
    __syncthreads();

    const int w  = tid >> 6;
    const int l  = tid & 63;
    const int eg = w >> 2, og = w & 3;
    const int e0 = eg * 64;
    const int lg = l >> 4;
    const int lm = l & 15;

    f32x4 acc[4][4];
#pragma unroll
    for (int i = 0; i < 4; ++i)
#pragma unroll
        for (int o = 0; o < 4; ++o) acc[i][o] = (f32x4){0.f, 0.f, 0.f, 0.f};

#pragma unroll
    for (int ks = 0; ks < 4; ++ks) {
        short8 bh[4], bl[4];
#pragma unroll
        for (int o = 0; o < 4; ++o) {
            size_t off = (size_t)(og * 64 + o * 16 + lm) * 128 + ks * 32 + lg * 8;
            bh[o] = *(const short8*)&Wh[off];
            bl[o] = *(const short8*)&Wl[off];
        }
        short8 ah[4], al[4];
#pragma unroll
        for (int i = 0; i < 4; ++i) {
            int row = e0 + i * 16 + lm;
            int cw = (ks * 4 + lg) ^ (row & 7);
            ah[i] = *(const short8*)&zsh[row * 128 + cw * 8];
            al[i] = *(const short8*)&zsl[row * 128 + cw * 8];
        }
#pragma unroll
        for (int i = 0; i < 4; ++i)
#pragma unroll
            for (int o = 0; o < 4; ++o) {
                acc[i][o] = __builtin_amdgcn_mfma_f32_16x16x32_bf16(ah[i], bh[o], acc[i][o], 0, 0, 0);
                acc[i][o] = __builtin_amdgcn_mfma_f32_16x16x32_bf16(al[i], bh[o], acc[i][o], 0, 0, 0);
                acc[i][o] = __builtin_amdgcn_mfma_f32_16x16x32_bf16(ah[i], bl[o], acc[i][o], 0, 0, 0);
            }
    }

    // ---- epilogue: att assembly, d-reduction across 16 lanes, write ----
#pragma unroll
    for (int hh = 0; hh < 2; ++hh) {
        int h = og * 2 + hh;
        float rxv = rx[n * 128 + h * 16 + lm];
#pragma unroll
        for (int i = 0; i < 4; ++i) {
            int mbase = m0 + e0 + i * 16 + lg * 4;
            float t[4];
#pragma unroll
            for (int r = 0; r < 4; ++r) {
                float ryv = ry[(size_t)(mbase + r) * 128 + h * 16 + lm];
                t[r] = (rxv + acc[i][hh * 2][r]) * (ryv + acc[i][hh * 2 + 1][r]);
            }
#pragma unroll
            for (int r = 0; r < 4; ++r) {
                t[r] += __shfl_xor(t[r], 1);
                t[r] += __shfl_xor(t[r], 2);
                t[r] += __shfl_xor(t[r], 4);
                t[r] += __shfl_xor(t[r], 8);
            }
            if (lm == 0) {
                int4 mk = *(const int4*)&mask[n * 512 + mbase];
                int mks[4] = {mk.x, mk.y, mk.z, mk.w};
                float4 o4;
                float* op = (float*)&o4;
#pragma unroll
                for (int r = 0; r < 4; ++r) {
                    float a = 10.f * tanhf(0.25f * t[r]);
                    op[r] = (mks[r] == 1) ? -INFINITY : a;
                }
                *(float4*)&att[((size_t)(h * 512 + n)) * 512 + mbase] = o4;
            }
        }
    }
}

// ---------------------------------------------------------------------------
// softpv: softmax over n per (h,m) + PV. Block = (64-m tile, h), 256 thr =
// 64 m-lanes x 4 n-strips of 128. Coalesced att reads; xp staged in LDS.
// ---------------------------------------------------------------------------
__global__ __launch_bounds__(256) void softpv_kernel(const float* __restrict__ att,
                                                     const float* __restrict__ xp,
                                                     float* __restrict__ rr) {
    __shared__ float xps[512][16];      // 32 KB
    __shared__ float red[4][64][16];    // 16 KB
    __shared__ float ssum[4][64];       // 1 KB
    const int m0 = blockIdx.x * 64;
    const int h  = blockIdx.y;
    const int t  = threadIdx.x;
    const int ml = t & 63, g = t >> 6;

    for (int idx = t; idx < 512 * 4; idx += 256) {
        int nn = idx >> 2, c = idx & 3;
        *(float4*)&xps[nn][c * 4] = *(const float4*)&xp[nn * 128 + h * 16 + c * 4];
    }
    __syncthreads();

    const float* col = &att[((size_t)h * 512) * 512 + m0 + ml];
    float mx = -INFINITY;
    for (int nn = g * 128; nn < g * 128 + 128; ++nn)
        mx = fmaxf(mx, col[(size_t)nn * 512]);
    ssum[g][ml] = mx;
    __syncthreads();
    mx = fmaxf(fmaxf(ssum[0][ml], ssum[1][ml]), fmaxf(ssum[2][ml], ssum[3][ml]));
    __syncthreads();

    float s = 0.f;
    float racc[16];
#pragma unroll
    for (int dd = 0; dd < 16; ++dd) racc[dd] = 0.f;
    for (int nn = g * 128; nn < g * 128 + 128; ++nn) {
        float e = __expf(col[(size_t)nn * 512] - mx);
        s += e;
#pragma unroll
        for (int c = 0; c < 4; ++c) {
            float4 xv = *(const float4*)&xps[nn][c * 4];
            racc[c * 4 + 0] = fmaf(e, xv.x, racc[c * 4 + 0]);
            racc[c * 4 + 1] = fmaf(e, xv.y, racc[c * 4 + 1]);
            racc[c * 4 + 2] = fmaf(e, xv.z, racc[c * 4 + 2]);
            racc[c * 4 + 3] = fmaf(e, xv.w, racc[c * 4 + 3]);
        }
    }
    ssum[g][ml] = s;
#pragma unroll
    for (int dd = 0; dd < 16; ++dd) red[g][ml][dd] = racc[dd];
    __syncthreads();

    float stot = ssum[0][ml] + ssum[1][ml] + ssum[2][ml] + ssum[3][ml];
    float inv = 1.f / stot;
    float4 o4;
    float* op = (float*)&o4;
#pragma unroll
    for (int j = 0; j < 4; ++j) {
        int dd = g * 4 + j;
        op[j] = (red[0][ml][dd] + red[1][ml][dd] + red[2][ml][dd] + red[3][ml][dd]) * inv;
    }
    *(float4*)&rr[(size_t)(m0 + ml) * 128 + h * 16 + g * 4] = o4;
}

// ---------------------------------------------------------------------------
// outg: out[m][q] = ob[q] + sum_o rr[m][o] * T2[o][q]
// ---------------------------------------------------------------------------
__global__ void outg_kernel(const float* __restrict__ rr,
                            const float* __restrict__ T2,
                            const float* __restrict__ ob,
                            float* __restrict__ out) {
    __shared__ float rrow[128];
    int m = blockIdx.x;
    int q = threadIdx.x;
    rrow[q] = rr[m * 128 + q];
    __syncthreads();
    float s = ob[q];
    for (int o = 0; o < 128; ++o)
        s = fmaf(rrow[o], T2[o * 128 + q], s);
    out[m * 128 + q] = s;
}

extern "C" void kernel_launch(void* const* d_in, const int* in_sizes, int n_in,
                              void* d_out, int out_size, void* d_ws, size_t ws_size,
                              hipStream_t stream) {
    (void)in_sizes; (void)n_in; (void)out_size; (void)ws_size;
    const float* x   = (const float*)d_in[0];
    const float* y   = (const float*)d_in[1];
    const float* z   = (const float*)d_in[2];
    const int*  mask = (const int*)d_in[3];
    const float* lx  = (const float*)d_in[4];
    const float* ly  = (const float*)d_in[5];
    const float* lz1 = (const float*)d_in[6];
    const float* lz2 = (const float*)d_in[7];
    const float* blx = (const float*)d_in[8];
    const float* bly = (const float*)d_in[9];
    const float* t1  = (const float*)d_in[10];
    const float* t2  = (const float*)d_in[11];
    const float* bth = (const float*)d_in[12];
    float* out = (float*)d_out;

    float* ws = (float*)d_ws;
    float* rx = ws;                              // 65536
    float* ry = rx + 65536;                      // 65536
    float* xp = ry + 65536;                      // 65536
    __hip_bfloat16* Wh = (__hip_bfloat16*)(xp + 65536);        // 32768 bf16
    __hip_bfloat16* Wl = (__hip_bfloat16*)(xp + 65536 + 16384);// 32768 bf16
    float* T2  = xp + 65536 + 32768;             // 16384
    float* ob  = T2 + 16384;                     // 128
    float* att = ob + 128;                       // 8*512*512
    float* rr  = att + 2097152;                  // 65536

    pack_kernel<<<dim3(32), dim3(256), 0, stream>>>(lz1, lz2, t2, bth, Wh, Wl, T2, ob);
    proj_kernel<<<dim3(512, 3), dim3(128), 0, stream>>>(x, y, lx, ly, t1, blx, bly, rx, ry, xp);
    big_kernel<<<dim3(4, 512), dim3(512), 0, stream>>>(z, mask, Wh, Wl, rx, ry, att);
    softpv_kernel<<<dim3(8, 8), dim3(256), 0, stream>>>(att, xp, rr);
    outg_kernel<<<dim3(512), dim3(128), 0, stream>>>(rr, T2, ob, out);
}

// Round 4
// 301.930 us; speedup vs baseline: 1.8155x; 1.2344x over previous
//
#include <hip/hip_runtime.h>
#include <hip/hip_bf16.h>
#include <math.h>

typedef __attribute__((ext_vector_type(8))) short short8;
typedef __attribute__((ext_vector_type(4))) float f32x4;

// ---------------------------------------------------------------------------
// pack: Wh/Wl[o'][q] bf16 hi/lo, o' = h*32 + which*16 + d  (which0=lambda_z1)
//       T2[o][q] = theta2[h][q][d];  ob[q] = sum bias_theta*theta2
//       Lp[which][q][o] packed proj weights (0=lambda_x,1=lambda_y,2=theta1)
// ---------------------------------------------------------------------------
__global__ void pack_kernel(const float* __restrict__ lz1,
                            const float* __restrict__ lz2,
                            const float* __restrict__ th2,
                            const float* __restrict__ bth,
                            const float* __restrict__ lx,
                            const float* __restrict__ ly,
                            const float* __restrict__ t1,
                            __hip_bfloat16* __restrict__ Wh,
                            __hip_bfloat16* __restrict__ Wl,
                            float* __restrict__ T2,
                            float* __restrict__ ob,
                            float* __restrict__ Lp) {
    int tid = blockIdx.x * blockDim.x + threadIdx.x;
    int stride = gridDim.x * blockDim.x;
    for (int i = tid; i < 256 * 128; i += stride) {
        int op = i >> 7, q = i & 127;
        int h = op >> 5, wh = (op >> 4) & 1, d = op & 15;
        float v = (wh ? lz2 : lz1)[(h * 128 + q) * 16 + d];
        __hip_bfloat16 hb = __float2bfloat16(v);
        Wh[i] = hb;
        Wl[i] = __float2bfloat16(v - __bfloat162float(hb));
    }
    for (int i = tid; i < 128 * 128; i += stride) {
        int o = i >> 7, q = i & 127;
        int h = o >> 4, d = o & 15;
        T2[i] = th2[(h * 128 + q) * 16 + d];
    }
    for (int i = tid; i < 3 * 128 * 128; i += stride) {
        int which = i >> 14, q = (i >> 7) & 127, o = i & 127;
        int h = o >> 4, d = o & 15;
        const float* S = (which == 0) ? lx : (which == 1) ? ly : t1;
        Lp[i] = S[(h * 128 + q) * 16 + d];
    }
    for (int q = tid; q < 128; q += stride) {
        float s = 0.f;
        for (int h = 0; h < 8; ++h)
            for (int d = 0; d < 16; ++d)
                s += bth[h * 16 + d] * th2[(h * 128 + q) * 16 + d];
        ob[q] = s;
    }
}

// ---------------------------------------------------------------------------
// proj: which=0: rx = x@lambda_x + b; 1: ry = y@lambda_y + b; 2: xp = x@theta1
// packed weights -> coalesced; 4 partial accumulators break the FMA chain
// ---------------------------------------------------------------------------
__global__ void proj_kernel(const float* __restrict__ x,
                            const float* __restrict__ y,
                            const float* __restrict__ Lp,
                            const float* __restrict__ blx,
                            const float* __restrict__ bly,
                            float* __restrict__ rx,
                            float* __restrict__ ry,
                            float* __restrict__ xp) {
    __shared__ float row[128];
    int n = blockIdx.x;
    int which = blockIdx.y;
    const float* in = (which == 1) ? y : x;
    const float* L  = Lp + which * 16384;
    int o = threadIdx.x;
    row[o] = in[n * 128 + o];
    __syncthreads();
    float a0 = 0.f, a1 = 0.f, a2 = 0.f, a3 = 0.f;
    for (int q = 0; q < 128; q += 4) {
        a0 = fmaf(row[q + 0], L[(q + 0) * 128 + o], a0);
        a1 = fmaf(row[q + 1], L[(q + 1) * 128 + o], a1);
        a2 = fmaf(row[q + 2], L[(q + 2) * 128 + o], a2);
        a3 = fmaf(row[q + 3], L[(q + 3) * 128 + o], a3);
    }
    float acc = (a0 + a1) + (a2 + a3);
    if (which == 0) acc += blx[o];
    if (which == 1) acc += bly[o];
    float* dst = (which == 0) ? rx : (which == 1) ? ry : xp;
    dst[n * 128 + o] = acc;
}

// ---------------------------------------------------------------------------
// big: block = (n, 64-m tile), 4 waves (og). bf16x3 MFMA z-proj with SWAPPED
// operands: D rows = d (outputs), D cols = edges -> d-reduce = in-reg + 2 shfl.
// Writes w = exp(att - 10) (unnormalized softmax numerator; masked -> 0).
// ---------------------------------------------------------------------------
__global__ __launch_bounds__(256) void big_kernel(
        const float* __restrict__ z,
        const int* __restrict__ mask,
        const __hip_bfloat16* __restrict__ Wh,
        const __hip_bfloat16* __restrict__ Wl,
        const float* __restrict__ rx,
        const float* __restrict__ ry,
        float* __restrict__ w) {
    __shared__ short zsh[64 * 128];   // 16 KB bf16-hi, XOR-swizzled 16B chunks
    __shared__ short zsl[64 * 128];   // 16 KB bf16-lo
    const int m0 = blockIdx.x * 64;
    const int n  = blockIdx.y;
    const int tid = threadIdx.x;

    // ---- stage z tile: fp32 -> bf16 hi/lo, swizzle chunk ^= (row&7) ----
    {
        const int row = tid >> 2, kseg = tid & 3;
        const float* src = &z[((size_t)(n * 512 + m0 + row)) * 128 + kseg * 32];
#pragma unroll
        for (int c8 = 0; c8 < 4; ++c8) {
            float4 v0 = *(const float4*)&src[c8 * 8 + 0];
            float4 v1 = *(const float4*)&src[c8 * 8 + 4];
            float vv[8] = {v0.x, v0.y, v0.z, v0.w, v1.x, v1.y, v1.z, v1.w};
            union { short8 s; __hip_bfloat16 h[8]; } uh, ul;
#pragma unroll
            for (int j = 0; j < 8; ++j) {
                float f = vv[j];
                __hip_bfloat16 hb = __float2bfloat16(f);
                uh.h[j] = hb;
                ul.h[j] = __float2bfloat16(f - __bfloat162float(hb));
            }
            int cw = (kseg * 4 + c8) ^ (row & 7);
            *(short8*)&zsh[row * 128 + cw * 8] = uh.s;
            *(short8*)&zsl[row * 128 + cw * 8] = ul.s;
        }
    }
    __syncthreads();

    const int og = tid >> 6;
    const int l  = tid & 63;
    const int lg = l >> 4;
    const int lm = l & 15;

    const int mk = mask[n * 512 + m0 + l];

#pragma unroll
    for (int p = 0; p < 2; ++p) {
        const int h = og * 2 + p;
        f32x4 acc[4][2];
#pragma unroll
        for (int i = 0; i < 4; ++i) {
            acc[i][0] = (f32x4){0.f, 0.f, 0.f, 0.f};
            acc[i][1] = (f32x4){0.f, 0.f, 0.f, 0.f};
        }

#pragma unroll
        for (int ks = 0; ks < 4; ++ks) {
            short8 bh[2], bl[2];
#pragma unroll
            for (int j = 0; j < 2; ++j) {
                size_t off = (size_t)(og * 64 + (p * 2 + j) * 16 + lm) * 128 + ks * 32 + lg * 8;
                bh[j] = *(const short8*)&Wh[off];
                bl[j] = *(const short8*)&Wl[off];
            }
            short8 ah[4], al[4];
#pragma unroll
            for (int i = 0; i < 4; ++i) {
                int row = i * 16 + lm;
                int cw = (ks * 4 + lg) ^ (row & 7);
                ah[i] = *(const short8*)&zsh[row * 128 + cw * 8];
                al[i] = *(const short8*)&zsl[row * 128 + cw * 8];
            }
#pragma unroll
            for (int i = 0; i < 4; ++i)
#pragma unroll
                for (int j = 0; j < 2; ++j) {
                    acc[i][j] = __builtin_amdgcn_mfma_f32_16x16x32_bf16(bh[j], ah[i], acc[i][j], 0, 0, 0);
                    acc[i][j] = __builtin_amdgcn_mfma_f32_16x16x32_bf16(bh[j], al[i], acc[i][j], 0, 0, 0);
                    acc[i][j] = __builtin_amdgcn_mfma_f32_16x16x32_bf16(bl[j], ah[i], acc[i][j], 0, 0, 0);
                }
        }

        // ---- epilogue: in-reg d-sum over r, 2 shfl over lg strata ----
        float4 rxt = *(const float4*)&rx[n * 128 + h * 16 + lg * 4];
        const float rxv[4] = {rxt.x, rxt.y, rxt.z, rxt.w};
        float t[4];
#pragma unroll
        for (int i = 0; i < 4; ++i) {
            float4 ryt = *(const float4*)&ry[(size_t)(m0 + i * 16 + lm) * 128 + h * 16 + lg * 4];
            const float ryv[4] = {ryt.x, ryt.y, ryt.z, ryt.w};
            float s = 0.f;
#pragma unroll
            for (int r = 0; r < 4; ++r)
                s = fmaf(rxv[r] + acc[i][0][r], ryv[r] + acc[i][1][r], s);
            s += __shfl_xor(s, 16);
            s += __shfl_xor(s, 32);
            t[i] = s;
        }
        // lane (lg,lm) keeps t[lg]  ->  m = m0 + l, fully coalesced store
        float ta = (lg & 1) ? t[1] : t[0];
        float tb = (lg & 1) ? t[3] : t[2];
        float s  = (lg & 2) ? tb : ta;
        // w = exp(10*tanh(0.25 s) - 10) = exp(-20/(exp(0.5 s)+1))
        float e1 = __expf(0.5f * s);
        float wv = __expf(-20.f / (e1 + 1.f));
        if (mk == 1) wv = 0.f;
        w[((size_t)(h * 512 + n)) * 512 + m0 + l] = wv;
    }
}

// ---------------------------------------------------------------------------
// softpv: one-pass: per (h,m): sum_n w[n], racc_d = sum_n w[n]*xp[n,d];
// rr = racc/sum. Block = (32-m tile, h), 256 thr = 32 m x 8 n-strips.
// ---------------------------------------------------------------------------
__global__ __launch_bounds__(256) void softpv_kernel(const float* __restrict__ w,
                                                     const float* __restrict__ xp,
                                                     float* __restrict__ rr) {
    __shared__ float xps[512][16];      // 32 KB
    __shared__ float red[8][32][16];    // 16 KB
    __shared__ float ssum[8][32];       // 1 KB
    const int m0 = blockIdx.x * 32;
    const int h  = blockIdx.y;
    const int t  = threadIdx.x;
    const int ml = t & 31, g = t >> 5;

    for (int idx = t; idx < 512 * 4; idx += 256) {
        int nn = idx >> 2, c = idx & 3;
        *(float4*)&xps[nn][c * 4] = *(const float4*)&xp[nn * 128 + h * 16 + c * 4];
    }
    __syncthreads();

    const float* col = &w[((size_t)h * 512) * 512 + m0 + ml];
    float s = 0.f;
    float racc[16];
#pragma unroll
    for (int dd = 0; dd < 16; ++dd) racc[dd] = 0.f;
    for (int nn = g * 64; nn < g * 64 + 64; ++nn) {
        float e = col[(size_t)nn * 512];
        s += e;
#pragma unroll
        for (int c = 0; c < 4; ++c) {
            float4 xv = *(const float4*)&xps[nn][c * 4];
            racc[c * 4 + 0] = fmaf(e, xv.x, racc[c * 4 + 0]);
            racc[c * 4 + 1] = fmaf(e, xv.y, racc[c * 4 + 1]);
            racc[c * 4 + 2] = fmaf(e, xv.z, racc[c * 4 + 2]);
            racc[c * 4 + 3] = fmaf(e, xv.w, racc[c * 4 + 3]);
        }
    }
    ssum[g][ml] = s;
#pragma unroll
    for (int dd = 0; dd < 16; ++dd) red[g][ml][dd] = racc[dd];
    __syncthreads();

    if (t < 128) {
        int ml2 = t & 31, dg = t >> 5;
        float stot = 0.f;
#pragma unroll
        for (int gg = 0; gg < 8; ++gg) stot += ssum[gg][ml2];
        float inv = 1.f / stot;
        float4 o4;
        float* op = (float*)&o4;
#pragma unroll
        for (int j = 0; j < 4; ++j) {
            int dd = dg * 4 + j;
            float v = 0.f;
#pragma unroll
            for (int gg = 0; gg < 8; ++gg) v += red[gg][ml2][dd];
            op[j] = v * inv;
        }
        *(float4*)&rr[(size_t)(m0 + ml2) * 128 + h * 16 + dg * 4] = o4;
    }
}

// ---------------------------------------------------------------------------
// outg: out[m][q] = ob[q] + sum_o rr[m][o] * T2[o][q]
// ---------------------------------------------------------------------------
__global__ void outg_kernel(const float* __restrict__ rr,
                            const float* __restrict__ T2,
                            const float* __restrict__ ob,
                            float* __restrict__ out) {
    __shared__ float rrow[128];
    int m = blockIdx.x;
    int q = threadIdx.x;
    rrow[q] = rr[m * 128 + q];
    __syncthreads();
    float a0 = 0.f, a1 = 0.f, a2 = 0.f, a3 = 0.f;
    for (int o = 0; o < 128; o += 4) {
        a0 = fmaf(rrow[o + 0], T2[(o + 0) * 128 + q], a0);
        a1 = fmaf(rrow[o + 1], T2[(o + 1) * 128 + q], a1);
        a2 = fmaf(rrow[o + 2], T2[(o + 2) * 128 + q], a2);
        a3 = fmaf(rrow[o + 3], T2[(o + 3) * 128 + q], a3);
    }
    out[m * 128 + q] = ob[q] + (a0 + a1) + (a2 + a3);
}

extern "C" void kernel_launch(void* const* d_in, const int* in_sizes, int n_in,
                              void* d_out, int out_size, void* d_ws, size_t ws_size,
                              hipStream_t stream) {
    (void)in_sizes; (void)n_in; (void)out_size; (void)ws_size;
    const float* x   = (const float*)d_in[0];
    const float* y   = (const float*)d_in[1];
    const float* z   = (const float*)d_in[2];
    const int*  mask = (const int*)d_in[3];
    const float* lx  = (const float*)d_in[4];
    const float* ly  = (const float*)d_in[5];
    const float* lz1 = (const float*)d_in[6];
    const float* lz2 = (const float*)d_in[7];
    const float* blx = (const float*)d_in[8];
    const float* bly = (const float*)d_in[9];
    const float* t1  = (const float*)d_in[10];
    const float* t2  = (const float*)d_in[11];
    const float* bth = (const float*)d_in[12];
    float* out = (float*)d_out;

    float* ws = (float*)d_ws;
    float* rx = ws;                               // 65536
    float* ry = rx + 65536;                       // 65536
    float* xp = ry + 65536;                       // 65536
    __hip_bfloat16* Wh = (__hip_bfloat16*)(xp + 65536);         // 32768 bf16
    __hip_bfloat16* Wl = (__hip_bfloat16*)(xp + 65536 + 16384); // 32768 bf16
    float* T2  = xp + 65536 + 32768;              // 16384
    float* ob  = T2 + 16384;                      // 128
    float* Lp  = ob + 128;                        // 49152
    float* wbuf= Lp + 49152;                      // 8*512*512 = 2097152
    float* rr  = wbuf + 2097152;                  // 65536

    pack_kernel<<<dim3(32), dim3(256), 0, stream>>>(lz1, lz2, t2, bth, lx, ly, t1,
                                                    Wh, Wl, T2, ob, Lp);
    proj_kernel<<<dim3(512, 3), dim3(128), 0, stream>>>(x, y, Lp, blx, bly, rx, ry, xp);
    big_kernel<<<dim3(8, 512), dim3(256), 0, stream>>>(z, mask, Wh, Wl, rx, ry, wbuf);
    softpv_kernel<<<dim3(16, 8), dim3(256), 0, stream>>>(wbuf, xp, rr);
    outg_kernel<<<dim3(512), dim3(128), 0, stream>>>(rr, T2, ob, out);
}